// Round 19
// baseline (142.126 us; speedup 1.0000x reference)
//
#include <hip/hip_runtime.h>

typedef _Float16 f16;
typedef _Float16 half8 __attribute__((ext_vector_type(8)));
typedef _Float16 half4v __attribute__((ext_vector_type(4)));
typedef __fp16 fp16x2 __attribute__((ext_vector_type(2)));
typedef float f32x4 __attribute__((ext_vector_type(4)));
typedef float f32x16 __attribute__((ext_vector_type(16)));
typedef unsigned uint4v __attribute__((ext_vector_type(4)));

#define MFMA16(a,b,c) __builtin_amdgcn_mfma_f32_16x16x32_f16((a),(b),(c),0,0,0)
#define MFMA32(a,b,c) __builtin_amdgcn_mfma_f32_32x32x16_f16((a),(b),(c),0,0,0)

__device__ __forceinline__ void gload_lds16(const f16* g, f16* l) {
    __builtin_amdgcn_global_load_lds(
        (const __attribute__((address_space(1))) unsigned int*)g,
        (__attribute__((address_space(3))) unsigned int*)l, 16, 0, 0);
}

__device__ __forceinline__ void plswap(unsigned &a, unsigned &b) {
    asm volatile("v_permlane32_swap_b32 %0, %1" : "+v"(a), "+v"(b));
}

__device__ __forceinline__ unsigned pk2(float a, float b) {
    return __builtin_bit_cast(unsigned, __builtin_amdgcn_cvt_pkrtz(a, b));
}

__device__ __forceinline__ float fexp2(float x) {
#if __has_builtin(__builtin_amdgcn_exp2f)
    return __builtin_amdgcn_exp2f(x);
#else
    return exp2f(x);
#endif
}

__device__ __forceinline__ float xswap32(float x, int hi) {
    unsigned a = __builtin_bit_cast(unsigned, x), b = a;
    asm volatile("v_permlane32_swap_b32 %0, %1" : "+v"(a), "+v"(b));
    return __builtin_bit_cast(float, hi ? a : b);
}

// ---------------- fused prep: cast x (blocks 0..6143) + transpose w_qkv (..7871) + w_proj ----------------
__global__ void prep_kernel(const float* __restrict__ x, f16* __restrict__ x_h,
                            const float* __restrict__ w_qkv, f16* __restrict__ w_qkv_t,
                            const float* __restrict__ w_proj, f16* __restrict__ w_proj_t)
{
    __shared__ f16 tile[32][33];
    const int bidx = blockIdx.x;
    if (bidx < 6144) {
        int i = bidx * 256 + threadIdx.x;
        float4 v = ((const float4*)x)[i];
        half4v h;
        h.x = (f16)v.x; h.y = (f16)v.y; h.z = (f16)v.z; h.w = (f16)v.w;
        ((half4v*)x_h)[i] = h;
        return;
    }
    const float* in;  f16* out;  int N, idx;
    if (bidx < 6144 + 1728) { idx = bidx - 6144; in = w_qkv;  out = w_qkv_t;  N = 2304; }
    else                    { idx = bidx - 7872; in = w_proj; out = w_proj_t; N = 768;  }
    const int K = 768;
    int n0 = (idx % (N / 32)) * 32, k0 = (idx / (N / 32)) * 32;
    int tx = threadIdx.x & 31, ty = threadIdx.x >> 5;
    for (int r = ty; r < 32; r += 8)
        tile[r][tx] = (f16)in[(size_t)(k0 + r) * N + (n0 + tx)];
    __syncthreads();
    for (int r = ty; r < 32; r += 8)
        out[(size_t)(n0 + r) * K + (k0 + tx)] = tile[tx][r];
}

// ---------------- qkv GEMM: 128x128, 2-buffer (32KB) -> 5 blocks/CU, all 1152 resident ----------------
__global__ __launch_bounds__(256, 5)
void gemm_qkv(const f16* __restrict__ A, const f16* __restrict__ Bt,
              f16* __restrict__ qbuf, f16* __restrict__ kbuf, f16* __restrict__ vtbuf)
{
    constexpr int K = 768;
    constexpr int NX = 18;
    constexpr int NWG = NX * 64;          // 1152
    __shared__ __align__(16) char smem[32768];
    f16* As = (f16*)smem;              // [2][128*32]
    f16* Bs = (f16*)(smem + 16384);    // [2][128*32]
    const int tid  = threadIdx.x;
    const int lane = tid & 63, wave = tid >> 6;
    const int wm = wave >> 1, wn = wave & 1;
    const int l15 = lane & 15, l4 = lane >> 4;

    const int bid = blockIdx.x;
    const int swz = (bid & 7) * (NWG / 8) + (bid >> 3);
    const int m0 = (swz / NX) * 128, n0 = (swz % NX) * 128;

    const int srow  = lane >> 2;
    const int sslot = lane & 3;

    f32x4 acc[4][4] = {};

    #define GSTAGE(buf, kt) do {                                                     \
        _Pragma("unroll")                                                            \
        for (int i = 0; i < 2; ++i) {                                                \
            int rbase = i * 64 + wave * 16;                                          \
            int row = rbase + srow;                                                  \
            gload_lds16(A  + (size_t)(m0 + row) * K + (kt) + sslot * 8, &As[(buf) * 4096 + rbase * 32]); \
            gload_lds16(Bt + (size_t)(n0 + row) * K + (kt) + sslot * 8, &Bs[(buf) * 4096 + rbase * 32]); \
        }                                                                            \
    } while (0)

    GSTAGE(0, 0);
    __syncthreads();

    for (int t = 0; t < 24; ++t) {
        const int cur = t & 1;
        if (t < 23) GSTAGE(cur ^ 1, (t + 1) * 32);
        half8 af[4], bf[4];
        #pragma unroll
        for (int mi = 0; mi < 4; mi++) af[mi] = *(const half8*)&As[cur*4096 + (wm*64 + mi*16 + l15) * 32 + l4*8];
        #pragma unroll
        for (int ni = 0; ni < 4; ni++) bf[ni] = *(const half8*)&Bs[cur*4096 + (wn*64 + ni*16 + l15) * 32 + l4*8];
        #pragma unroll
        for (int mi = 0; mi < 4; mi++)
            #pragma unroll
            for (int ni = 0; ni < 4; ni++)
                acc[mi][ni] = MFMA16(af[mi], bf[ni], acc[mi][ni]);
        __syncthreads();   // drains vmcnt (next tile ready) + guards buffer reuse
    }
    #undef GSTAGE

    // ---- epilogue: LDS roundtrip in two halves (fits 32KB) ----
    const int t3 = n0 / 768;
    const int bb = m0 >> 10;
    const int mo = m0 & 1023;
    const int h0 = (n0 - t3 * 768) >> 6;

    if (t3 < 2) {
        f16* sC = (f16*)smem;          // [64][136] per half
        f16* outb = (t3 == 0) ? qbuf : kbuf;
        #pragma unroll
        for (int hh = 0; hh < 2; hh++) {
            if (wm == hh) {
                #pragma unroll
                for (int mi = 0; mi < 4; mi++)
                    #pragma unroll
                    for (int ni = 0; ni < 4; ni++)
                        #pragma unroll
                        for (int r = 0; r < 4; r++) {
                            int row = mi*16 + l4*4 + r;          // local 0..63
                            int col = wn*64 + ni*16 + l15;
                            sC[row * 136 + col] = (f16)acc[mi][ni][r];
                        }
            }
            __syncthreads();
            #pragma unroll
            for (int hc = 0; hc < 2; hc++) {
                f16* base = outb + ((size_t)(bb * 12 + h0 + hc) * 1024 + mo + hh * 64) * 64;
                #pragma unroll
                for (int i = 0; i < 2; i++) {
                    int row = i * 32 + (tid >> 3);               // local 0..63
                    int cc  = (tid & 7) * 8;
                    half8 v = *(const half8*)&sC[row * 136 + hc * 64 + cc];
                    *(half8*)(base + row * 64 + cc) = v;
                }
            }
            __syncthreads();
        }
    } else {
        f16* sC = (f16*)smem;          // [64 cols][136] per half
        #pragma unroll
        for (int hh = 0; hh < 2; hh++) {
            if (wn == hh) {
                #pragma unroll
                for (int mi = 0; mi < 4; mi++)
                    #pragma unroll
                    for (int ni = 0; ni < 4; ni++) {
                        int row0 = wm*64 + mi*16 + l4*4;
                        int col  = ni*16 + l15;                  // local 0..63
                        half4v pk;
                        #pragma unroll
                        for (int r = 0; r < 4; r++) pk[r] = (f16)acc[mi][ni][r];
                        *(half4v*)&sC[col * 136 + row0] = pk;
                    }
            }
            __syncthreads();
            #pragma unroll
            for (int i = 0; i < 4; i++) {
                int col = i * 16 + (tid >> 4);                   // local 0..63
                int rc  = (tid & 15) * 8;
                half8 v = *(const half8*)&sC[col * 136 + rc];
                int colg = hh * 64 + col;
                int head = h0 + (colg >> 6), dd = colg & 63;
                *(half8*)(vtbuf + ((size_t)(bb * 12 + head) * 64 + dd) * 1024 + mo + rc) = v;
            }
            __syncthreads();
        }
    }
}

// ---------------- proj GEMM (R16-proven): 128x128, NX=6, 3-buffer counted vmcnt ----------------
__global__ __launch_bounds__(256, 3)
void gemm_proj(const f16* __restrict__ A, const f16* __restrict__ Bt,
               float* __restrict__ out, const float* __restrict__ bias)
{
    constexpr int K = 768;
    constexpr int NX = 6;
    constexpr int NWG = NX * 64;
    __shared__ __align__(16) char smem[49152];
    f16* As = (f16*)smem;
    f16* Bs = (f16*)(smem + 24576);
    const int tid  = threadIdx.x;
    const int lane = tid & 63, wave = tid >> 6;
    const int wm = wave >> 1, wn = wave & 1;
    const int l15 = lane & 15, l4 = lane >> 4;

    const int bid = blockIdx.x;
    const int swz = (bid & 7) * (NWG / 8) + (bid >> 3);
    const int m0 = (swz / NX) * 128, n0 = (swz % NX) * 128;

    const int srow  = lane >> 2;
    const int sslot = lane & 3;

    f32x4 acc[4][4] = {};

    #define GSTAGE(buf, kt) do {                                                     \
        _Pragma("unroll")                                                            \
        for (int i = 0; i < 2; ++i) {                                                \
            int rbase = i * 64 + wave * 16;                                          \
            int row = rbase + srow;                                                  \
            gload_lds16(A  + (size_t)(m0 + row) * K + (kt) + sslot * 8, &As[(buf) * 4096 + rbase * 32]); \
            gload_lds16(Bt + (size_t)(n0 + row) * K + (kt) + sslot * 8, &Bs[(buf) * 4096 + rbase * 32]); \
        }                                                                            \
    } while (0)

    GSTAGE(0, 0);
    GSTAGE(1, 32);

    int cur = 0;
    for (int t = 0; t < 24; ++t) {
        if (t < 23) asm volatile("s_waitcnt vmcnt(4)" ::: "memory");
        else        asm volatile("s_waitcnt vmcnt(0)" ::: "memory");
        __builtin_amdgcn_s_barrier();
        if (t < 22) {
            int nb = cur + 2; if (nb >= 3) nb -= 3;
            GSTAGE(nb, (t + 2) * 32);
        }
        half8 af[4], bf[4];
        #pragma unroll
        for (int mi = 0; mi < 4; mi++) af[mi] = *(const half8*)&As[cur*4096 + (wm*64 + mi*16 + l15) * 32 + l4*8];
        #pragma unroll
        for (int ni = 0; ni < 4; ni++) bf[ni] = *(const half8*)&Bs[cur*4096 + (wn*64 + ni*16 + l15) * 32 + l4*8];
        #pragma unroll
        for (int mi = 0; mi < 4; mi++)
            #pragma unroll
            for (int ni = 0; ni < 4; ni++)
                acc[mi][ni] = MFMA16(af[mi], bf[ni], acc[mi][ni]);
        if (++cur >= 3) cur = 0;
    }
    #undef GSTAGE

    #pragma unroll
    for (int mi = 0; mi < 4; mi++)
        #pragma unroll
        for (int ni = 0; ni < 4; ni++)
            #pragma unroll
            for (int r = 0; r < 4; r++) {
                int gm = m0 + wm*64 + mi*16 + l4*4 + r;
                int gn = n0 + wn*64 + ni*16 + l15;
                out[(size_t)gm * 768 + gn] = acc[mi][ni][r] + bias[gn];
            }
}

// ---------------- flash attention: 3-buffer QK-ahead pipeline, native exp, 32x32 MFMA ----------------
__global__ __launch_bounds__(256, 3)
void attn_kernel(const f16* __restrict__ qbuf, const f16* __restrict__ kbuf,
                 const f16* __restrict__ vtbuf, f16* __restrict__ obuf)
{
    __shared__ __align__(16) f16 Ks[3][4096];
    __shared__ __align__(16) f16 Vs[3][4096];
    const int tid = threadIdx.x;
    const int lane = tid & 63, wave = tid >> 6;
    const int bh = blockIdx.x;
    const int b = bh / 12, h = bh % 12;
    const int q0 = blockIdx.y * 128 + wave * 32;
    const int l31 = lane & 31, hi = lane >> 5;
    const int sw0 = (l31 & 7) << 4;

    const f16* Q  = qbuf  + (size_t)bh * 65536;
    const f16* Kp = kbuf  + (size_t)bh * 65536;
    const f16* Vt = vtbuf + (size_t)bh * 65536;

    const f16 slh = (f16)(0.125f * 1.44269504089f);
    half8 aq[4];
    #pragma unroll
    for (int c = 0; c < 4; c++) {
        aq[c] = *(const half8*)&Q[(size_t)(q0 + l31) * 64 + c * 16 + hi * 8];
        #pragma unroll
        for (int j = 0; j < 8; j++) aq[c][j] *= slh;
    }

    const int srow8 = lane >> 3;
    const int c16   = (lane & 7) ^ srow8;

    f32x16 o0 = {}, o1 = {};
    float lrq = 0.f, mrq = 0.f, stale = 0.f;

    #define STAGE(buf, kv) do {                                                     \
        _Pragma("unroll")                                                           \
        for (int i = 0; i < 2; ++i) {                                               \
            int rbase = wave * 16 + i * 8;                                          \
            int rl = rbase + srow8;                                                 \
            gload_lds16(Kp + (size_t)((kv) + rl) * 64 + c16 * 8, &Ks[buf][rbase * 64]); \
            gload_lds16(Vt + (size_t)rl * 1024 + (kv) + c16 * 8, &Vs[buf][rbase * 64]); \
        }                                                                           \
    } while (0)

    #define QKISSUE(dst0, dst1, kb, minit) do {                                     \
        _Pragma("unroll")                                                           \
        for (int j = 0; j < 16; j++) { dst0[j] = (minit); dst1[j] = (minit); }      \
        __builtin_amdgcn_s_setprio(1);                                              \
        _Pragma("unroll")                                                           \
        for (int c = 0; c < 4; c++) {                                               \
            int koff = (c * 32 + hi * 16) ^ sw0;                                    \
            half8 k0 = *(const half8*)((kb) + l31 * 128 + koff);                    \
            half8 k1 = *(const half8*)((kb) + (32 + l31) * 128 + koff);             \
            dst0 = MFMA32(k0, aq[c], dst0);                                         \
            dst1 = MFMA32(k1, aq[c], dst1);                                         \
        }                                                                           \
        __builtin_amdgcn_s_setprio(0);                                              \
    } while (0)

    STAGE(0, 0);
    STAGE(1, 64);
    __syncthreads();

    f32x16 st0, st1;
    QKISSUE(st0, st1, (const char*)&Ks[0][0], 0.f);

    int bcur = 0;
    for (int t = 0; t < 16; ++t) {
        int bn1 = bcur + 1; if (bn1 >= 3) bn1 -= 3;
        int bn2 = bcur + 2; if (bn2 >= 3) bn2 -= 3;

        if (t < 14) STAGE(bn2, (t + 2) * 64);

        f32x16 sN0, sN1;
        if (t < 15) QKISSUE(sN0, sN1, (const char*)&Ks[bn1][0], -mrq);

        if (__any(stale != 0.f)) {
            #pragma unroll
            for (int j = 0; j < 16; j++) { st0[j] -= stale; st1[j] -= stale; }
        }
        stale = 0.f;

        float m16;
        {
            float p0 = fmaxf(fmaxf(st0[0],  st0[1]),  fmaxf(st0[2],  st0[3]));
            float p1 = fmaxf(fmaxf(st0[4],  st0[5]),  fmaxf(st0[6],  st0[7]));
            float p2 = fmaxf(fmaxf(st0[8],  st0[9]),  fmaxf(st0[10], st0[11]));
            float p3 = fmaxf(fmaxf(st0[12], st0[13]), fmaxf(st0[14], st0[15]));
            float r0 = fmaxf(fmaxf(st1[0],  st1[1]),  fmaxf(st1[2],  st1[3]));
            float r1 = fmaxf(fmaxf(st1[4],  st1[5]),  fmaxf(st1[6],  st1[7]));
            float r2 = fmaxf(fmaxf(st1[8],  st1[9]),  fmaxf(st1[10], st1[11]));
            float r3 = fmaxf(fmaxf(st1[12], st1[13]), fmaxf(st1[14], st1[15]));
            m16 = fmaxf(fmaxf(fmaxf(p0, p1), fmaxf(p2, p3)),
                        fmaxf(fmaxf(r0, r1), fmaxf(r2, r3)));
        }
        m16 = fmaxf(m16, xswap32(m16, hi));

        if (!__all(m16 <= 11.0f)) {
            float d = fmaxf(m16, 0.f);
            float alpha = fexp2(-d);
            mrq += d;
            stale = d;
            #pragma unroll
            for (int j = 0; j < 16; j++) { st0[j] -= d; st1[j] -= d; }
            lrq *= alpha;
            #pragma unroll
            for (int reg = 0; reg < 16; reg++) {
                float a = __shfl(alpha, (reg & 3) + 8 * (reg >> 2) + 4 * hi);
                o0[reg] *= a; o1[reg] *= a;
            }
        }

        float rs = 0.f;
        half8 pa[4];
        #pragma unroll
        for (int tile = 0; tile < 2; tile++) {
            const f32x16& sv = tile ? st1 : st0;
            #pragma unroll
            for (int half16 = 0; half16 < 2; half16++) {
                int rb = half16 * 8;
                unsigned A1, B1, A2, B2;
                {
                    float e0 = fexp2(sv[rb+0]), e1 = fexp2(sv[rb+1]);
                    float e4 = fexp2(sv[rb+4]), e5 = fexp2(sv[rb+5]);
                    rs += (e0 + e1) + (e4 + e5);
                    A1 = pk2(e0, e1); B1 = pk2(e4, e5);
                    plswap(A1, B1);
                }
                {
                    float e2 = fexp2(sv[rb+2]), e3 = fexp2(sv[rb+3]);
                    float e6 = fexp2(sv[rb+6]), e7 = fexp2(sv[rb+7]);
                    rs += (e2 + e3) + (e6 + e7);
                    A2 = pk2(e2, e3); B2 = pk2(e6, e7);
                    plswap(A2, B2);
                }
                uint4v w = {A1, A2, B1, B2};
                pa[tile * 2 + half16] = __builtin_bit_cast(half8, w);
            }
        }
        rs += xswap32(rs, hi);
        lrq += rs;

        {
            const char* Vb = (const char*)&Vs[bcur][0];
            __builtin_amdgcn_s_setprio(1);
            #pragma unroll
            for (int kc = 0; kc < 4; kc++) {
                int koff = (kc * 32 + hi * 16) ^ sw0;
                half8 v0 = *(const half8*)(Vb + l31 * 128 + koff);
                half8 v1 = *(const half8*)(Vb + (32 + l31) * 128 + koff);
                o0 = MFMA32(pa[kc], v0, o0);
                o1 = MFMA32(pa[kc], v1, o1);
            }
            __builtin_amdgcn_s_setprio(0);
        }

        if (t < 15) {
            asm volatile("s_waitcnt vmcnt(0)" ::: "memory");
            __builtin_amdgcn_s_barrier();
            st0 = sN0; st1 = sN1;
        }
        bcur = bn1;
    }
    #undef QKISSUE
    #undef STAGE

    float rq = 1.0f / lrq;
    f16* Op = obuf + (size_t)b * 1024 * 768 + h * 64;
    #pragma unroll
    for (int reg = 0; reg < 16; reg++) {
        int qrow = (reg & 3) + 8 * (reg >> 2) + 4 * hi;
        float inv = __shfl(rq, qrow);
        size_t base = (size_t)(q0 + qrow) * 768;
        Op[base + l31]      = (f16)(o0[reg] * inv);
        Op[base + 32 + l31] = (f16)(o1[reg] * inv);
    }
}

extern "C" void kernel_launch(void* const* d_in, const int* in_sizes, int n_in,
                              void* d_out, int out_size, void* d_ws, size_t ws_size,
                              hipStream_t stream) {
    const float* x      = (const float*)d_in[0];
    const float* w_qkv  = (const float*)d_in[1];
    const float* w_proj = (const float*)d_in[2];
    const float* b_proj = (const float*)d_in[3];
    float* out = (float*)d_out;
    char* ws = (char*)d_ws;

    f16* x_h      = (f16*)(ws + 0);
    f16* w_qkv_t  = (f16*)(ws + 12582912);
    f16* w_proj_t = (f16*)(ws + 16121856);
    f16* qb       = (f16*)(ws + 17301504);
    f16* kb       = (f16*)(ws + 29884416);
    f16* vtb      = (f16*)(ws + 42467328);
    f16* ob       = (f16*)(ws + 55050240);

    prep_kernel<<<dim3(6144 + 1728 + 576), dim3(256), 0, stream>>>(
        x, x_h, w_qkv, w_qkv_t, w_proj, w_proj_t);
    gemm_qkv<<<dim3(18 * 64), dim3(256), 0, stream>>>(x_h, w_qkv_t, qb, kb, vtb);
    attn_kernel<<<dim3(96, 8), dim3(256), 0, stream>>>(qb, kb, vtb, ob);
    gemm_proj<<<dim3(6 * 64), dim3(256), 0, stream>>>(ob, w_proj_t, out, b_proj);
}

// Round 20
// 117.970 us; speedup vs baseline: 1.2048x; 1.2048x over previous
//
#include <hip/hip_runtime.h>

typedef _Float16 f16;
typedef _Float16 half8 __attribute__((ext_vector_type(8)));
typedef _Float16 half4v __attribute__((ext_vector_type(4)));
typedef __fp16 fp16x2 __attribute__((ext_vector_type(2)));
typedef float f32x4 __attribute__((ext_vector_type(4)));
typedef float f32x16 __attribute__((ext_vector_type(16)));
typedef unsigned uint4v __attribute__((ext_vector_type(4)));

#define MFMA16(a,b,c) __builtin_amdgcn_mfma_f32_16x16x32_f16((a),(b),(c),0,0,0)
#define MFMA32(a,b,c) __builtin_amdgcn_mfma_f32_32x32x16_f16((a),(b),(c),0,0,0)

__device__ __forceinline__ void gload_lds16(const f16* g, f16* l) {
    __builtin_amdgcn_global_load_lds(
        (const __attribute__((address_space(1))) unsigned int*)g,
        (__attribute__((address_space(3))) unsigned int*)l, 16, 0, 0);
}

__device__ __forceinline__ void plswap(unsigned &a, unsigned &b) {
    asm volatile("v_permlane32_swap_b32 %0, %1" : "+v"(a), "+v"(b));
}

__device__ __forceinline__ unsigned pk2(float a, float b) {
    return __builtin_bit_cast(unsigned, __builtin_amdgcn_cvt_pkrtz(a, b));
}

__device__ __forceinline__ float fexp2(float x) {
#if __has_builtin(__builtin_amdgcn_exp2f)
    return __builtin_amdgcn_exp2f(x);
#else
    return exp2f(x);
#endif
}

__device__ __forceinline__ float xswap32(float x, int hi) {
    unsigned a = __builtin_bit_cast(unsigned, x), b = a;
    asm volatile("v_permlane32_swap_b32 %0, %1" : "+v"(a), "+v"(b));
    return __builtin_bit_cast(float, hi ? a : b);
}

// ---------------- fused prep: cast x (blocks 0..6143) + transpose w_qkv (..7871) + w_proj ----------------
__global__ void prep_kernel(const float* __restrict__ x, f16* __restrict__ x_h,
                            const float* __restrict__ w_qkv, f16* __restrict__ w_qkv_t,
                            const float* __restrict__ w_proj, f16* __restrict__ w_proj_t)
{
    __shared__ f16 tile[32][33];
    const int bidx = blockIdx.x;
    if (bidx < 6144) {
        int i = bidx * 256 + threadIdx.x;
        float4 v = ((const float4*)x)[i];
        half4v h;
        h.x = (f16)v.x; h.y = (f16)v.y; h.z = (f16)v.z; h.w = (f16)v.w;
        ((half4v*)x_h)[i] = h;
        return;
    }
    const float* in;  f16* out;  int N, idx;
    if (bidx < 6144 + 1728) { idx = bidx - 6144; in = w_qkv;  out = w_qkv_t;  N = 2304; }
    else                    { idx = bidx - 7872; in = w_proj; out = w_proj_t; N = 768;  }
    const int K = 768;
    int n0 = (idx % (N / 32)) * 32, k0 = (idx / (N / 32)) * 32;
    int tx = threadIdx.x & 31, ty = threadIdx.x >> 5;
    for (int r = ty; r < 32; r += 8)
        tile[r][tx] = (f16)in[(size_t)(k0 + r) * N + (n0 + tx)];
    __syncthreads();
    for (int r = ty; r < 32; r += 8)
        out[(size_t)(n0 + r) * K + (k0 + tx)] = tile[tx][r];
}

// ---------------- qkv GEMM (proven 47.4us): 128x128, 3-buffer counted vmcnt, LDS epilogue ----------------
__global__ __launch_bounds__(256, 3)
void gemm_qkv(const f16* __restrict__ A, const f16* __restrict__ Bt,
              f16* __restrict__ qbuf, f16* __restrict__ kbuf, f16* __restrict__ vtbuf)
{
    constexpr int K = 768;
    constexpr int NX = 18;
    constexpr int NWG = NX * 64;          // 1152
    __shared__ __align__(16) char smem[49152];
    f16* As = (f16*)smem;              // [3][128*32]
    f16* Bs = (f16*)(smem + 24576);    // [3][128*32]
    const int tid  = threadIdx.x;
    const int lane = tid & 63, wave = tid >> 6;
    const int wm = wave >> 1, wn = wave & 1;
    const int l15 = lane & 15, l4 = lane >> 4;

    const int bid = blockIdx.x;
    const int swz = (bid & 7) * (NWG / 8) + (bid >> 3);
    const int m0 = (swz / NX) * 128, n0 = (swz % NX) * 128;

    const int srow  = lane >> 2;
    const int sslot = lane & 3;

    f32x4 acc[4][4] = {};

    #define GSTAGE(buf, kt) do {                                                     \
        _Pragma("unroll")                                                            \
        for (int i = 0; i < 2; ++i) {                                                \
            int rbase = i * 64 + wave * 16;                                          \
            int row = rbase + srow;                                                  \
            gload_lds16(A  + (size_t)(m0 + row) * K + (kt) + sslot * 8, &As[(buf) * 4096 + rbase * 32]); \
            gload_lds16(Bt + (size_t)(n0 + row) * K + (kt) + sslot * 8, &Bs[(buf) * 4096 + rbase * 32]); \
        }                                                                            \
    } while (0)

    GSTAGE(0, 0);
    GSTAGE(1, 32);

    int cur = 0;
    for (int t = 0; t < 24; ++t) {
        if (t < 23) asm volatile("s_waitcnt vmcnt(4)" ::: "memory");
        else        asm volatile("s_waitcnt vmcnt(0)" ::: "memory");
        __builtin_amdgcn_s_barrier();
        if (t < 22) {
            int nb = cur + 2; if (nb >= 3) nb -= 3;
            GSTAGE(nb, (t + 2) * 32);
        }
        half8 af[4], bf[4];
        #pragma unroll
        for (int mi = 0; mi < 4; mi++) af[mi] = *(const half8*)&As[cur*4096 + (wm*64 + mi*16 + l15) * 32 + l4*8];
        #pragma unroll
        for (int ni = 0; ni < 4; ni++) bf[ni] = *(const half8*)&Bs[cur*4096 + (wn*64 + ni*16 + l15) * 32 + l4*8];
        #pragma unroll
        for (int mi = 0; mi < 4; mi++)
            #pragma unroll
            for (int ni = 0; ni < 4; ni++)
                acc[mi][ni] = MFMA16(af[mi], bf[ni], acc[mi][ni]);
        if (++cur >= 3) cur = 0;
    }
    #undef GSTAGE

    // ---- epilogue: LDS roundtrip -> coalesced stores ----
    __syncthreads();
    f16* sC = (f16*)smem;          // [128][136]
    const int t3 = n0 / 768;
    const int bb = m0 >> 10;
    const int mo = m0 & 1023;
    const int h0 = (n0 - t3 * 768) >> 6;

    if (t3 < 2) {
        #pragma unroll
        for (int mi = 0; mi < 4; mi++)
            #pragma unroll
            for (int ni = 0; ni < 4; ni++)
                #pragma unroll
                for (int r = 0; r < 4; r++) {
                    int row = wm*64 + mi*16 + l4*4 + r;
                    int col = wn*64 + ni*16 + l15;
                    sC[row * 136 + col] = (f16)acc[mi][ni][r];
                }
        __syncthreads();
        f16* outb = (t3 == 0) ? qbuf : kbuf;
        #pragma unroll
        for (int hc = 0; hc < 2; hc++) {
            f16* base = outb + ((size_t)(bb * 12 + h0 + hc) * 1024 + mo) * 64;
            #pragma unroll
            for (int i = 0; i < 4; i++) {
                int row = wave * 32 + i * 8 + (lane >> 3);
                int cc  = (lane & 7) * 8;
                half8 v = *(const half8*)&sC[row * 136 + hc * 64 + cc];
                *(half8*)(base + row * 64 + cc) = v;
            }
        }
    } else {
        #pragma unroll
        for (int mi = 0; mi < 4; mi++)
            #pragma unroll
            for (int ni = 0; ni < 4; ni++) {
                int row0 = wm*64 + mi*16 + l4*4;
                int col  = wn*64 + ni*16 + l15;
                half4v pk;
                #pragma unroll
                for (int r = 0; r < 4; r++) pk[r] = (f16)acc[mi][ni][r];
                *(half4v*)&sC[col * 136 + row0] = pk;
            }
        __syncthreads();
        #pragma unroll
        for (int i = 0; i < 8; i++) {
            int col = wave * 32 + i * 4 + (lane >> 4);
            int rc  = (lane & 15) * 8;
            half8 v = *(const half8*)&sC[col * 136 + rc];
            int head = h0 + (col >> 6), dd = col & 63;
            *(half8*)(vtbuf + ((size_t)(bb * 12 + head) * 64 + dd) * 1024 + mo + rc) = v;
        }
    }
}

// ---------------- proj GEMM (R16-proven): 128x128, NX=6, 3-buffer counted vmcnt ----------------
__global__ __launch_bounds__(256, 3)
void gemm_proj(const f16* __restrict__ A, const f16* __restrict__ Bt,
               float* __restrict__ out, const float* __restrict__ bias)
{
    constexpr int K = 768;
    constexpr int NX = 6;
    constexpr int NWG = NX * 64;
    __shared__ __align__(16) char smem[49152];
    f16* As = (f16*)smem;
    f16* Bs = (f16*)(smem + 24576);
    const int tid  = threadIdx.x;
    const int lane = tid & 63, wave = tid >> 6;
    const int wm = wave >> 1, wn = wave & 1;
    const int l15 = lane & 15, l4 = lane >> 4;

    const int bid = blockIdx.x;
    const int swz = (bid & 7) * (NWG / 8) + (bid >> 3);
    const int m0 = (swz / NX) * 128, n0 = (swz % NX) * 128;

    const int srow  = lane >> 2;
    const int sslot = lane & 3;

    f32x4 acc[4][4] = {};

    #define GSTAGE(buf, kt) do {                                                     \
        _Pragma("unroll")                                                            \
        for (int i = 0; i < 2; ++i) {                                                \
            int rbase = i * 64 + wave * 16;                                          \
            int row = rbase + srow;                                                  \
            gload_lds16(A  + (size_t)(m0 + row) * K + (kt) + sslot * 8, &As[(buf) * 4096 + rbase * 32]); \
            gload_lds16(Bt + (size_t)(n0 + row) * K + (kt) + sslot * 8, &Bs[(buf) * 4096 + rbase * 32]); \
        }                                                                            \
    } while (0)

    GSTAGE(0, 0);
    GSTAGE(1, 32);

    int cur = 0;
    for (int t = 0; t < 24; ++t) {
        if (t < 23) asm volatile("s_waitcnt vmcnt(4)" ::: "memory");
        else        asm volatile("s_waitcnt vmcnt(0)" ::: "memory");
        __builtin_amdgcn_s_barrier();
        if (t < 22) {
            int nb = cur + 2; if (nb >= 3) nb -= 3;
            GSTAGE(nb, (t + 2) * 32);
        }
        half8 af[4], bf[4];
        #pragma unroll
        for (int mi = 0; mi < 4; mi++) af[mi] = *(const half8*)&As[cur*4096 + (wm*64 + mi*16 + l15) * 32 + l4*8];
        #pragma unroll
        for (int ni = 0; ni < 4; ni++) bf[ni] = *(const half8*)&Bs[cur*4096 + (wn*64 + ni*16 + l15) * 32 + l4*8];
        #pragma unroll
        for (int mi = 0; mi < 4; mi++)
            #pragma unroll
            for (int ni = 0; ni < 4; ni++)
                acc[mi][ni] = MFMA16(af[mi], bf[ni], acc[mi][ni]);
        if (++cur >= 3) cur = 0;
    }
    #undef GSTAGE

    #pragma unroll
    for (int mi = 0; mi < 4; mi++)
        #pragma unroll
        for (int ni = 0; ni < 4; ni++)
            #pragma unroll
            for (int r = 0; r < 4; r++) {
                int gm = m0 + wm*64 + mi*16 + l4*4 + r;
                int gn = n0 + wn*64 + ni*16 + l15;
                out[(size_t)gm * 768 + gn] = acc[mi][ni][r] + bias[gn];
            }
}

// ---------------- flash attention: 3-buffer QK-ahead pipeline, native exp, 32x32 MFMA ----------------
__global__ __launch_bounds__(256, 3)
void attn_kernel(const f16* __restrict__ qbuf, const f16* __restrict__ kbuf,
                 const f16* __restrict__ vtbuf, f16* __restrict__ obuf)
{
    __shared__ __align__(16) f16 Ks[3][4096];
    __shared__ __align__(16) f16 Vs[3][4096];
    const int tid = threadIdx.x;
    const int lane = tid & 63, wave = tid >> 6;
    const int bh = blockIdx.x;
    const int b = bh / 12, h = bh % 12;
    const int q0 = blockIdx.y * 128 + wave * 32;
    const int l31 = lane & 31, hi = lane >> 5;
    const int sw0 = (l31 & 7) << 4;

    const f16* Q  = qbuf  + (size_t)bh * 65536;
    const f16* Kp = kbuf  + (size_t)bh * 65536;
    const f16* Vt = vtbuf + (size_t)bh * 65536;

    const f16 slh = (f16)(0.125f * 1.44269504089f);
    half8 aq[4];
    #pragma unroll
    for (int c = 0; c < 4; c++) {
        aq[c] = *(const half8*)&Q[(size_t)(q0 + l31) * 64 + c * 16 + hi * 8];
        #pragma unroll
        for (int j = 0; j < 8; j++) aq[c][j] *= slh;
    }

    const int srow8 = lane >> 3;
    const int c16   = (lane & 7) ^ srow8;

    f32x16 o0 = {}, o1 = {};
    float lrq = 0.f, mrq = 0.f, stale = 0.f;

    #define STAGE(buf, kv) do {                                                     \
        _Pragma("unroll")                                                           \
        for (int i = 0; i < 2; ++i) {                                               \
            int rbase = wave * 16 + i * 8;                                          \
            int rl = rbase + srow8;                                                 \
            gload_lds16(Kp + (size_t)((kv) + rl) * 64 + c16 * 8, &Ks[buf][rbase * 64]); \
            gload_lds16(Vt + (size_t)rl * 1024 + (kv) + c16 * 8, &Vs[buf][rbase * 64]); \
        }                                                                           \
    } while (0)

    #define QKISSUE(dst0, dst1, kb, minit) do {                                     \
        _Pragma("unroll")                                                           \
        for (int j = 0; j < 16; j++) { dst0[j] = (minit); dst1[j] = (minit); }      \
        __builtin_amdgcn_s_setprio(1);                                              \
        _Pragma("unroll")                                                           \
        for (int c = 0; c < 4; c++) {                                               \
            int koff = (c * 32 + hi * 16) ^ sw0;                                    \
            half8 k0 = *(const half8*)((kb) + l31 * 128 + koff);                    \
            half8 k1 = *(const half8*)((kb) + (32 + l31) * 128 + koff);             \
            dst0 = MFMA32(k0, aq[c], dst0);                                         \
            dst1 = MFMA32(k1, aq[c], dst1);                                         \
        }                                                                           \
        __builtin_amdgcn_s_setprio(0);                                              \
    } while (0)

    STAGE(0, 0);
    STAGE(1, 64);
    __syncthreads();

    f32x16 st0, st1;
    QKISSUE(st0, st1, (const char*)&Ks[0][0], 0.f);

    int bcur = 0;
    for (int t = 0; t < 16; ++t) {
        int bn1 = bcur + 1; if (bn1 >= 3) bn1 -= 3;
        int bn2 = bcur + 2; if (bn2 >= 3) bn2 -= 3;

        if (t < 14) STAGE(bn2, (t + 2) * 64);

        f32x16 sN0, sN1;
        if (t < 15) QKISSUE(sN0, sN1, (const char*)&Ks[bn1][0], -mrq);

        if (__any(stale != 0.f)) {
            #pragma unroll
            for (int j = 0; j < 16; j++) { st0[j] -= stale; st1[j] -= stale; }
        }
        stale = 0.f;

        float m16;
        {
            float p0 = fmaxf(fmaxf(st0[0],  st0[1]),  fmaxf(st0[2],  st0[3]));
            float p1 = fmaxf(fmaxf(st0[4],  st0[5]),  fmaxf(st0[6],  st0[7]));
            float p2 = fmaxf(fmaxf(st0[8],  st0[9]),  fmaxf(st0[10], st0[11]));
            float p3 = fmaxf(fmaxf(st0[12], st0[13]), fmaxf(st0[14], st0[15]));
            float r0 = fmaxf(fmaxf(st1[0],  st1[1]),  fmaxf(st1[2],  st1[3]));
            float r1 = fmaxf(fmaxf(st1[4],  st1[5]),  fmaxf(st1[6],  st1[7]));
            float r2 = fmaxf(fmaxf(st1[8],  st1[9]),  fmaxf(st1[10], st1[11]));
            float r3 = fmaxf(fmaxf(st1[12], st1[13]), fmaxf(st1[14], st1[15]));
            m16 = fmaxf(fmaxf(fmaxf(p0, p1), fmaxf(p2, p3)),
                        fmaxf(fmaxf(r0, r1), fmaxf(r2, r3)));
        }
        m16 = fmaxf(m16, xswap32(m16, hi));

        if (!__all(m16 <= 11.0f)) {
            float d = fmaxf(m16, 0.f);
            float alpha = fexp2(-d);
            mrq += d;
            stale = d;
            #pragma unroll
            for (int j = 0; j < 16; j++) { st0[j] -= d; st1[j] -= d; }
            lrq *= alpha;
            #pragma unroll
            for (int reg = 0; reg < 16; reg++) {
                float a = __shfl(alpha, (reg & 3) + 8 * (reg >> 2) + 4 * hi);
                o0[reg] *= a; o1[reg] *= a;
            }
        }

        float rs = 0.f;
        half8 pa[4];
        #pragma unroll
        for (int tile = 0; tile < 2; tile++) {
            const f32x16& sv = tile ? st1 : st0;
            #pragma unroll
            for (int half16 = 0; half16 < 2; half16++) {
                int rb = half16 * 8;
                unsigned A1, B1, A2, B2;
                {
                    float e0 = fexp2(sv[rb+0]), e1 = fexp2(sv[rb+1]);
                    float e4 = fexp2(sv[rb+4]), e5 = fexp2(sv[rb+5]);
                    rs += (e0 + e1) + (e4 + e5);
                    A1 = pk2(e0, e1); B1 = pk2(e4, e5);
                    plswap(A1, B1);
                }
                {
                    float e2 = fexp2(sv[rb+2]), e3 = fexp2(sv[rb+3]);
                    float e6 = fexp2(sv[rb+6]), e7 = fexp2(sv[rb+7]);
                    rs += (e2 + e3) + (e6 + e7);
                    A2 = pk2(e2, e3); B2 = pk2(e6, e7);
                    plswap(A2, B2);
                }
                uint4v w = {A1, A2, B1, B2};
                pa[tile * 2 + half16] = __builtin_bit_cast(half8, w);
            }
        }
        rs += xswap32(rs, hi);
        lrq += rs;

        {
            const char* Vb = (const char*)&Vs[bcur][0];
            __builtin_amdgcn_s_setprio(1);
            #pragma unroll
            for (int kc = 0; kc < 4; kc++) {
                int koff = (kc * 32 + hi * 16) ^ sw0;
                half8 v0 = *(const half8*)(Vb + l31 * 128 + koff);
                half8 v1 = *(const half8*)(Vb + (32 + l31) * 128 + koff);
                o0 = MFMA32(pa[kc], v0, o0);
                o1 = MFMA32(pa[kc], v1, o1);
            }
            __builtin_amdgcn_s_setprio(0);
        }

        if (t < 15) {
            asm volatile("s_waitcnt vmcnt(0)" ::: "memory");
            __builtin_amdgcn_s_barrier();
            st0 = sN0; st1 = sN1;
        }
        bcur = bn1;
    }
    #undef QKISSUE
    #undef STAGE

    float rq = 1.0f / lrq;
    f16* Op = obuf + (size_t)b * 1024 * 768 + h * 64;
    #pragma unroll
    for (int reg = 0; reg < 16; reg++) {
        int qrow = (reg & 3) + 8 * (reg >> 2) + 4 * hi;
        float inv = __shfl(rq, qrow);
        size_t base = (size_t)(q0 + qrow) * 768;
        Op[base + l31]      = (f16)(o0[reg] * inv);
        Op[base + 32 + l31] = (f16)(o1[reg] * inv);
    }
}

extern "C" void kernel_launch(void* const* d_in, const int* in_sizes, int n_in,
                              void* d_out, int out_size, void* d_ws, size_t ws_size,
                              hipStream_t stream) {
    const float* x      = (const float*)d_in[0];
    const float* w_qkv  = (const float*)d_in[1];
    const float* w_proj = (const float*)d_in[2];
    const float* b_proj = (const float*)d_in[3];
    float* out = (float*)d_out;
    char* ws = (char*)d_ws;

    f16* x_h      = (f16*)(ws + 0);
    f16* w_qkv_t  = (f16*)(ws + 12582912);
    f16* w_proj_t = (f16*)(ws + 16121856);
    f16* qb       = (f16*)(ws + 17301504);
    f16* kb       = (f16*)(ws + 29884416);
    f16* vtb      = (f16*)(ws + 42467328);
    f16* ob       = (f16*)(ws + 55050240);

    prep_kernel<<<dim3(6144 + 1728 + 576), dim3(256), 0, stream>>>(
        x, x_h, w_qkv, w_qkv_t, w_proj, w_proj_t);
    gemm_qkv<<<dim3(18 * 64), dim3(256), 0, stream>>>(x_h, w_qkv_t, qb, kb, vtb);
    attn_kernel<<<dim3(96, 8), dim3(256), 0, stream>>>(qb, kb, vtb, ob);
    gemm_proj<<<dim3(6 * 64), dim3(256), 0, stream>>>(ob, w_proj_t, out, b_proj);
}

// Round 21
// 117.006 us; speedup vs baseline: 1.2147x; 1.0082x over previous
//
#include <hip/hip_runtime.h>

typedef _Float16 f16;
typedef _Float16 half8 __attribute__((ext_vector_type(8)));
typedef _Float16 half4v __attribute__((ext_vector_type(4)));
typedef __fp16 fp16x2 __attribute__((ext_vector_type(2)));
typedef float f32x4 __attribute__((ext_vector_type(4)));
typedef float f32x16 __attribute__((ext_vector_type(16)));
typedef unsigned uint4v __attribute__((ext_vector_type(4)));

#define MFMA16(a,b,c) __builtin_amdgcn_mfma_f32_16x16x32_f16((a),(b),(c),0,0,0)
#define MFMA32(a,b,c) __builtin_amdgcn_mfma_f32_32x32x16_f16((a),(b),(c),0,0,0)

__device__ __forceinline__ void gload_lds16(const f16* g, f16* l) {
    __builtin_amdgcn_global_load_lds(
        (const __attribute__((address_space(1))) unsigned int*)g,
        (__attribute__((address_space(3))) unsigned int*)l, 16, 0, 0);
}

__device__ __forceinline__ void plswap(unsigned &a, unsigned &b) {
    asm volatile("v_permlane32_swap_b32 %0, %1" : "+v"(a), "+v"(b));
}

__device__ __forceinline__ unsigned pk2(float a, float b) {
    return __builtin_bit_cast(unsigned, __builtin_amdgcn_cvt_pkrtz(a, b));
}

__device__ __forceinline__ float fexp2(float x) {
#if __has_builtin(__builtin_amdgcn_exp2f)
    return __builtin_amdgcn_exp2f(x);
#else
    return exp2f(x);
#endif
}

__device__ __forceinline__ float xswap32(float x, int hi) {
    unsigned a = __builtin_bit_cast(unsigned, x), b = a;
    asm volatile("v_permlane32_swap_b32 %0, %1" : "+v"(a), "+v"(b));
    return __builtin_bit_cast(float, hi ? a : b);
}

// ---------------- fused prep: cast x (blocks 0..6143) + transpose w_qkv (..7871) + w_proj ----------------
__global__ void prep_kernel(const float* __restrict__ x, f16* __restrict__ x_h,
                            const float* __restrict__ w_qkv, f16* __restrict__ w_qkv_t,
                            const float* __restrict__ w_proj, f16* __restrict__ w_proj_t)
{
    __shared__ f16 tile[32][33];
    const int bidx = blockIdx.x;
    if (bidx < 6144) {
        int i = bidx * 256 + threadIdx.x;
        float4 v = ((const float4*)x)[i];
        half4v h;
        h.x = (f16)v.x; h.y = (f16)v.y; h.z = (f16)v.z; h.w = (f16)v.w;
        ((half4v*)x_h)[i] = h;
        return;
    }
    const float* in;  f16* out;  int N, idx;
    if (bidx < 6144 + 1728) { idx = bidx - 6144; in = w_qkv;  out = w_qkv_t;  N = 2304; }
    else                    { idx = bidx - 7872; in = w_proj; out = w_proj_t; N = 768;  }
    const int K = 768;
    int n0 = (idx % (N / 32)) * 32, k0 = (idx / (N / 32)) * 32;
    int tx = threadIdx.x & 31, ty = threadIdx.x >> 5;
    for (int r = ty; r < 32; r += 8)
        tile[r][tx] = (f16)in[(size_t)(k0 + r) * N + (n0 + tx)];
    __syncthreads();
    for (int r = ty; r < 32; r += 8)
        out[(size_t)(n0 + r) * K + (k0 + tx)] = tile[tx][r];
}

// ---------------- qkv GEMM (proven 47.0us): 128x128, 3-buffer counted vmcnt, LDS epilogue ----------------
__global__ __launch_bounds__(256, 3)
void gemm_qkv(const f16* __restrict__ A, const f16* __restrict__ Bt,
              f16* __restrict__ qbuf, f16* __restrict__ kbuf, f16* __restrict__ vtbuf)
{
    constexpr int K = 768;
    constexpr int NX = 18;
    constexpr int NWG = NX * 64;          // 1152
    __shared__ __align__(16) char smem[49152];
    f16* As = (f16*)smem;              // [3][128*32]
    f16* Bs = (f16*)(smem + 24576);    // [3][128*32]
    const int tid  = threadIdx.x;
    const int lane = tid & 63, wave = tid >> 6;
    const int wm = wave >> 1, wn = wave & 1;
    const int l15 = lane & 15, l4 = lane >> 4;

    const int bid = blockIdx.x;
    const int swz = (bid & 7) * (NWG / 8) + (bid >> 3);
    const int m0 = (swz / NX) * 128, n0 = (swz % NX) * 128;

    const int srow  = lane >> 2;
    const int sslot = lane & 3;

    f32x4 acc[4][4] = {};

    #define GSTAGE(buf, kt) do {                                                     \
        _Pragma("unroll")                                                            \
        for (int i = 0; i < 2; ++i) {                                                \
            int rbase = i * 64 + wave * 16;                                          \
            int row = rbase + srow;                                                  \
            gload_lds16(A  + (size_t)(m0 + row) * K + (kt) + sslot * 8, &As[(buf) * 4096 + rbase * 32]); \
            gload_lds16(Bt + (size_t)(n0 + row) * K + (kt) + sslot * 8, &Bs[(buf) * 4096 + rbase * 32]); \
        }                                                                            \
    } while (0)

    GSTAGE(0, 0);
    GSTAGE(1, 32);

    int cur = 0;
    for (int t = 0; t < 24; ++t) {
        if (t < 23) asm volatile("s_waitcnt vmcnt(4)" ::: "memory");
        else        asm volatile("s_waitcnt vmcnt(0)" ::: "memory");
        __builtin_amdgcn_s_barrier();
        if (t < 22) {
            int nb = cur + 2; if (nb >= 3) nb -= 3;
            GSTAGE(nb, (t + 2) * 32);
        }
        half8 af[4], bf[4];
        #pragma unroll
        for (int mi = 0; mi < 4; mi++) af[mi] = *(const half8*)&As[cur*4096 + (wm*64 + mi*16 + l15) * 32 + l4*8];
        #pragma unroll
        for (int ni = 0; ni < 4; ni++) bf[ni] = *(const half8*)&Bs[cur*4096 + (wn*64 + ni*16 + l15) * 32 + l4*8];
        #pragma unroll
        for (int mi = 0; mi < 4; mi++)
            #pragma unroll
            for (int ni = 0; ni < 4; ni++)
                acc[mi][ni] = MFMA16(af[mi], bf[ni], acc[mi][ni]);
        if (++cur >= 3) cur = 0;
    }
    #undef GSTAGE

    // ---- epilogue: LDS roundtrip -> coalesced stores ----
    __syncthreads();
    f16* sC = (f16*)smem;          // [128][136]
    const int t3 = n0 / 768;
    const int bb = m0 >> 10;
    const int mo = m0 & 1023;
    const int h0 = (n0 - t3 * 768) >> 6;

    if (t3 < 2) {
        #pragma unroll
        for (int mi = 0; mi < 4; mi++)
            #pragma unroll
            for (int ni = 0; ni < 4; ni++)
                #pragma unroll
                for (int r = 0; r < 4; r++) {
                    int row = wm*64 + mi*16 + l4*4 + r;
                    int col = wn*64 + ni*16 + l15;
                    sC[row * 136 + col] = (f16)acc[mi][ni][r];
                }
        __syncthreads();
        f16* outb = (t3 == 0) ? qbuf : kbuf;
        #pragma unroll
        for (int hc = 0; hc < 2; hc++) {
            f16* base = outb + ((size_t)(bb * 12 + h0 + hc) * 1024 + mo) * 64;
            #pragma unroll
            for (int i = 0; i < 4; i++) {
                int row = wave * 32 + i * 8 + (lane >> 3);
                int cc  = (lane & 7) * 8;
                half8 v = *(const half8*)&sC[row * 136 + hc * 64 + cc];
                *(half8*)(base + row * 64 + cc) = v;
            }
        }
    } else {
        #pragma unroll
        for (int mi = 0; mi < 4; mi++)
            #pragma unroll
            for (int ni = 0; ni < 4; ni++) {
                int row0 = wm*64 + mi*16 + l4*4;
                int col  = wn*64 + ni*16 + l15;
                half4v pk;
                #pragma unroll
                for (int r = 0; r < 4; r++) pk[r] = (f16)acc[mi][ni][r];
                *(half4v*)&sC[col * 136 + row0] = pk;
            }
        __syncthreads();
        #pragma unroll
        for (int i = 0; i < 8; i++) {
            int col = wave * 32 + i * 4 + (lane >> 4);
            int rc  = (lane & 15) * 8;
            half8 v = *(const half8*)&sC[col * 136 + rc];
            int head = h0 + (col >> 6), dd = col & 63;
            *(half8*)(vtbuf + ((size_t)(bb * 12 + head) * 64 + dd) * 1024 + mo + rc) = v;
        }
    }
}

// ---------------- proj GEMM (R16-proven): 128x128, NX=6, 3-buffer counted vmcnt ----------------
__global__ __launch_bounds__(256, 3)
void gemm_proj(const f16* __restrict__ A, const f16* __restrict__ Bt,
               float* __restrict__ out, const float* __restrict__ bias)
{
    constexpr int K = 768;
    constexpr int NX = 6;
    constexpr int NWG = NX * 64;
    __shared__ __align__(16) char smem[49152];
    f16* As = (f16*)smem;
    f16* Bs = (f16*)(smem + 24576);
    const int tid  = threadIdx.x;
    const int lane = tid & 63, wave = tid >> 6;
    const int wm = wave >> 1, wn = wave & 1;
    const int l15 = lane & 15, l4 = lane >> 4;

    const int bid = blockIdx.x;
    const int swz = (bid & 7) * (NWG / 8) + (bid >> 3);
    const int m0 = (swz / NX) * 128, n0 = (swz % NX) * 128;

    const int srow  = lane >> 2;
    const int sslot = lane & 3;

    f32x4 acc[4][4] = {};

    #define GSTAGE(buf, kt) do {                                                     \
        _Pragma("unroll")                                                            \
        for (int i = 0; i < 2; ++i) {                                                \
            int rbase = i * 64 + wave * 16;                                          \
            int row = rbase + srow;                                                  \
            gload_lds16(A  + (size_t)(m0 + row) * K + (kt) + sslot * 8, &As[(buf) * 4096 + rbase * 32]); \
            gload_lds16(Bt + (size_t)(n0 + row) * K + (kt) + sslot * 8, &Bs[(buf) * 4096 + rbase * 32]); \
        }                                                                            \
    } while (0)

    GSTAGE(0, 0);
    GSTAGE(1, 32);

    int cur = 0;
    for (int t = 0; t < 24; ++t) {
        if (t < 23) asm volatile("s_waitcnt vmcnt(4)" ::: "memory");
        else        asm volatile("s_waitcnt vmcnt(0)" ::: "memory");
        __builtin_amdgcn_s_barrier();
        if (t < 22) {
            int nb = cur + 2; if (nb >= 3) nb -= 3;
            GSTAGE(nb, (t + 2) * 32);
        }
        half8 af[4], bf[4];
        #pragma unroll
        for (int mi = 0; mi < 4; mi++) af[mi] = *(const half8*)&As[cur*4096 + (wm*64 + mi*16 + l15) * 32 + l4*8];
        #pragma unroll
        for (int ni = 0; ni < 4; ni++) bf[ni] = *(const half8*)&Bs[cur*4096 + (wn*64 + ni*16 + l15) * 32 + l4*8];
        #pragma unroll
        for (int mi = 0; mi < 4; mi++)
            #pragma unroll
            for (int ni = 0; ni < 4; ni++)
                acc[mi][ni] = MFMA16(af[mi], bf[ni], acc[mi][ni]);
        if (++cur >= 3) cur = 0;
    }
    #undef GSTAGE

    #pragma unroll
    for (int mi = 0; mi < 4; mi++)
        #pragma unroll
        for (int ni = 0; ni < 4; ni++)
            #pragma unroll
            for (int r = 0; r < 4; r++) {
                int gm = m0 + wm*64 + mi*16 + l4*4 + r;
                int gn = n0 + wn*64 + ni*16 + l15;
                out[(size_t)gm * 768 + gn] = acc[mi][ni][r] + bias[gn];
            }
}

// ---------------- flash attention: 3-buffer QK-ahead pipeline + counted vmcnt (T4) ----------------
__global__ __launch_bounds__(256, 3)
void attn_kernel(const f16* __restrict__ qbuf, const f16* __restrict__ kbuf,
                 const f16* __restrict__ vtbuf, f16* __restrict__ obuf)
{
    __shared__ __align__(16) f16 Ks[3][4096];
    __shared__ __align__(16) f16 Vs[3][4096];
    const int tid = threadIdx.x;
    const int lane = tid & 63, wave = tid >> 6;
    const int bh = blockIdx.x;
    const int b = bh / 12, h = bh % 12;
    const int q0 = blockIdx.y * 128 + wave * 32;
    const int l31 = lane & 31, hi = lane >> 5;
    const int sw0 = (l31 & 7) << 4;

    const f16* Q  = qbuf  + (size_t)bh * 65536;
    const f16* Kp = kbuf  + (size_t)bh * 65536;
    const f16* Vt = vtbuf + (size_t)bh * 65536;

    const f16 slh = (f16)(0.125f * 1.44269504089f);
    half8 aq[4];
    #pragma unroll
    for (int c = 0; c < 4; c++) {
        aq[c] = *(const half8*)&Q[(size_t)(q0 + l31) * 64 + c * 16 + hi * 8];
        #pragma unroll
        for (int j = 0; j < 8; j++) aq[c][j] *= slh;
    }

    const int srow8 = lane >> 3;
    const int c16   = (lane & 7) ^ srow8;

    f32x16 o0 = {}, o1 = {};
    float lrq = 0.f, mrq = 0.f, stale = 0.f;

    #define STAGE(buf, kv) do {                                                     \
        _Pragma("unroll")                                                           \
        for (int i = 0; i < 2; ++i) {                                               \
            int rbase = wave * 16 + i * 8;                                          \
            int rl = rbase + srow8;                                                 \
            gload_lds16(Kp + (size_t)((kv) + rl) * 64 + c16 * 8, &Ks[buf][rbase * 64]); \
            gload_lds16(Vt + (size_t)rl * 1024 + (kv) + c16 * 8, &Vs[buf][rbase * 64]); \
        }                                                                           \
    } while (0)

    #define QKISSUE(dst0, dst1, kb, minit) do {                                     \
        _Pragma("unroll")                                                           \
        for (int j = 0; j < 16; j++) { dst0[j] = (minit); dst1[j] = (minit); }      \
        __builtin_amdgcn_s_setprio(1);                                              \
        _Pragma("unroll")                                                           \
        for (int c = 0; c < 4; c++) {                                               \
            int koff = (c * 32 + hi * 16) ^ sw0;                                    \
            half8 k0 = *(const half8*)((kb) + l31 * 128 + koff);                    \
            half8 k1 = *(const half8*)((kb) + (32 + l31) * 128 + koff);             \
            dst0 = MFMA32(k0, aq[c], dst0);                                         \
            dst1 = MFMA32(k1, aq[c], dst1);                                         \
        }                                                                           \
        __builtin_amdgcn_s_setprio(0);                                              \
    } while (0)

    STAGE(0, 0);
    STAGE(1, 64);
    __syncthreads();

    f32x16 st0, st1;
    QKISSUE(st0, st1, (const char*)&Ks[0][0], 0.f);

    int bcur = 0;
    for (int t = 0; t < 16; ++t) {
        int bn1 = bcur + 1; if (bn1 >= 3) bn1 -= 3;
        int bn2 = bcur + 2; if (bn2 >= 3) bn2 -= 3;

        if (t < 14) STAGE(bn2, (t + 2) * 64);

        f32x16 sN0, sN1;
        if (t < 15) QKISSUE(sN0, sN1, (const char*)&Ks[bn1][0], -mrq);

        if (__any(stale != 0.f)) {
            #pragma unroll
            for (int j = 0; j < 16; j++) { st0[j] -= stale; st1[j] -= stale; }
        }
        stale = 0.f;

        float m16;
        {
            float p0 = fmaxf(fmaxf(st0[0],  st0[1]),  fmaxf(st0[2],  st0[3]));
            float p1 = fmaxf(fmaxf(st0[4],  st0[5]),  fmaxf(st0[6],  st0[7]));
            float p2 = fmaxf(fmaxf(st0[8],  st0[9]),  fmaxf(st0[10], st0[11]));
            float p3 = fmaxf(fmaxf(st0[12], st0[13]), fmaxf(st0[14], st0[15]));
            float r0 = fmaxf(fmaxf(st1[0],  st1[1]),  fmaxf(st1[2],  st1[3]));
            float r1 = fmaxf(fmaxf(st1[4],  st1[5]),  fmaxf(st1[6],  st1[7]));
            float r2 = fmaxf(fmaxf(st1[8],  st1[9]),  fmaxf(st1[10], st1[11]));
            float r3 = fmaxf(fmaxf(st1[12], st1[13]), fmaxf(st1[14], st1[15]));
            m16 = fmaxf(fmaxf(fmaxf(p0, p1), fmaxf(p2, p3)),
                        fmaxf(fmaxf(r0, r1), fmaxf(r2, r3)));
        }
        m16 = fmaxf(m16, xswap32(m16, hi));

        if (!__all(m16 <= 11.0f)) {
            float d = fmaxf(m16, 0.f);
            float alpha = fexp2(-d);
            mrq += d;
            stale = d;
            #pragma unroll
            for (int j = 0; j < 16; j++) { st0[j] -= d; st1[j] -= d; }
            lrq *= alpha;
            #pragma unroll
            for (int reg = 0; reg < 16; reg++) {
                float a = __shfl(alpha, (reg & 3) + 8 * (reg >> 2) + 4 * hi);
                o0[reg] *= a; o1[reg] *= a;
            }
        }

        float rs = 0.f;
        half8 pa[4];
        #pragma unroll
        for (int tile = 0; tile < 2; tile++) {
            const f32x16& sv = tile ? st1 : st0;
            #pragma unroll
            for (int half16 = 0; half16 < 2; half16++) {
                int rb = half16 * 8;
                unsigned A1, B1, A2, B2;
                {
                    float e0 = fexp2(sv[rb+0]), e1 = fexp2(sv[rb+1]);
                    float e4 = fexp2(sv[rb+4]), e5 = fexp2(sv[rb+5]);
                    rs += (e0 + e1) + (e4 + e5);
                    A1 = pk2(e0, e1); B1 = pk2(e4, e5);
                    plswap(A1, B1);
                }
                {
                    float e2 = fexp2(sv[rb+2]), e3 = fexp2(sv[rb+3]);
                    float e6 = fexp2(sv[rb+6]), e7 = fexp2(sv[rb+7]);
                    rs += (e2 + e3) + (e6 + e7);
                    A2 = pk2(e2, e3); B2 = pk2(e6, e7);
                    plswap(A2, B2);
                }
                uint4v w = {A1, A2, B1, B2};
                pa[tile * 2 + half16] = __builtin_bit_cast(half8, w);
            }
        }
        rs += xswap32(rs, hi);
        lrq += rs;

        {
            const char* Vb = (const char*)&Vs[bcur][0];
            __builtin_amdgcn_s_setprio(1);
            #pragma unroll
            for (int kc = 0; kc < 4; kc++) {
                int koff = (kc * 32 + hi * 16) ^ sw0;
                half8 v0 = *(const half8*)(Vb + l31 * 128 + koff);
                half8 v1 = *(const half8*)(Vb + (32 + l31) * 128 + koff);
                o0 = MFMA32(pa[kc], v0, o0);
                o1 = MFMA32(pa[kc], v1, o1);
            }
            __builtin_amdgcn_s_setprio(0);
        }

        if (t < 15) {
            // counted vmcnt (T4): leave STAGE(t+2)'s 4 loads in flight; wait only
            // for tile t+1's 4 (the oldest outstanding). t=14 staged nothing -> drain.
            if (t < 14) asm volatile("s_waitcnt vmcnt(4)" ::: "memory");
            else        asm volatile("s_waitcnt vmcnt(0)" ::: "memory");
            __builtin_amdgcn_s_barrier();
            st0 = sN0; st1 = sN1;
        }
        bcur = bn1;
    }
    #undef QKISSUE
    #undef STAGE

    float rq = 1.0f / lrq;
    f16* Op = obuf + (size_t)b * 1024 * 768 + h * 64;
    #pragma unroll
    for (int reg = 0; reg < 16; reg++) {
        int qrow = (reg & 3) + 8 * (reg >> 2) + 4 * hi;
        float inv = __shfl(rq, qrow);
        size_t base = (size_t)(q0 + qrow) * 768;
        Op[base + l31]      = (f16)(o0[reg] * inv);
        Op[base + 32 + l31] = (f16)(o1[reg] * inv);
    }
}

extern "C" void kernel_launch(void* const* d_in, const int* in_sizes, int n_in,
                              void* d_out, int out_size, void* d_ws, size_t ws_size,
                              hipStream_t stream) {
    const float* x      = (const float*)d_in[0];
    const float* w_qkv  = (const float*)d_in[1];
    const float* w_proj = (const float*)d_in[2];
    const float* b_proj = (const float*)d_in[3];
    float* out = (float*)d_out;
    char* ws = (char*)d_ws;

    f16* x_h      = (f16*)(ws + 0);
    f16* w_qkv_t  = (f16*)(ws + 12582912);
    f16* w_proj_t = (f16*)(ws + 16121856);
    f16* qb       = (f16*)(ws + 17301504);
    f16* kb       = (f16*)(ws + 29884416);
    f16* vtb      = (f16*)(ws + 42467328);
    f16* ob       = (f16*)(ws + 55050240);

    prep_kernel<<<dim3(6144 + 1728 + 576), dim3(256), 0, stream>>>(
        x, x_h, w_qkv, w_qkv_t, w_proj, w_proj_t);
    gemm_qkv<<<dim3(18 * 64), dim3(256), 0, stream>>>(x_h, w_qkv_t, qb, kb, vtb);
    attn_kernel<<<dim3(96, 8), dim3(256), 0, stream>>>(qb, kb, vtb, ob);
    gemm_proj<<<dim3(6 * 64), dim3(256), 0, stream>>>(ob, w_proj_t, out, b_proj);
}